// Round 12
// baseline (242.083 us; speedup 1.0000x reference)
//
#include <hip/hip_runtime.h>
#include <math.h>

#define T_LEN  65536
#define C_CH   64
#define STEP_  256
#define K_     257        // WS/2 + 1
#define FPI    32         // frames per iteration (32 groups of 16 lanes)
#define NIT    8          // iterations
#define TPITCH 276        // T row pitch in float2 (16*17 = 272 + pad)
#define SPITCH 33         // spec row pitch in float2 (32 frames + 1)

#define CFENCE() asm volatile("" ::: "memory")
// barrier that does NOT drain vmcnt: prefetch loads stay in flight
#define BAR() do { asm volatile("s_waitcnt lgkmcnt(0)" ::: "memory"); \
                   __builtin_amdgcn_s_barrier(); \
                   asm volatile("" ::: "memory"); } while (0)

__device__ __forceinline__ float2 cadd(float2 a, float2 b) { return make_float2(a.x + b.x, a.y + b.y); }
__device__ __forceinline__ float2 csub(float2 a, float2 b) { return make_float2(a.x - b.x, a.y - b.y); }
__device__ __forceinline__ float2 cmul(float2 a, float2 b) {
    return make_float2(a.x * b.x - a.y * b.y, a.x * b.y + a.y * b.x);
}
// SGN>0: w*t ; SGN<0: conj(w)*t
template <int SGN>
__device__ __forceinline__ float2 cmulsg(float2 w, float2 t) {
    if (SGN > 0) return make_float2(w.x * t.x - w.y * t.y, w.x * t.y + w.y * t.x);
    else         return make_float2(w.x * t.x + w.y * t.y, w.x * t.y - w.y * t.x);
}
// radix-4 DFT, no twiddle. SGN=+1: e^-, SGN=-1: e^+
template <int SGN>
__device__ __forceinline__ void bfly4nt(float2 z0, float2 z1, float2 z2, float2 z3,
                                        float2& o0, float2& o1, float2& o2, float2& o3) {
    float2 apc = cadd(z0, z2), amc = csub(z0, z2);
    float2 bpd = cadd(z1, z3), bmd = csub(z1, z3);
    float2 jb  = make_float2(-bmd.y, bmd.x);
    o0 = cadd(apc, bpd);
    o2 = csub(apc, bpd);
    if (SGN > 0) { o1 = csub(amc, jb); o3 = cadd(amc, jb); }
    else         { o1 = cadd(amc, jb); o3 = csub(amc, jb); }
}

// In-register DFT-16 (y[j] = sum_m W16^{SGN*mj} v[m], W16=e^{-2pi i/16}).
// Two radix-4 stages; constants conjugated via cmulsg<SGN>.
template <int SGN>
__device__ __forceinline__ void dft16(float2* v) {
    const float C1 = 0.9238795325112867f, S1 = 0.3826834323650898f, R2 = 0.7071067811865476f;
    const float2 W1 = make_float2(C1, -S1);
    const float2 W2 = make_float2(R2, -R2);
    const float2 W3 = make_float2(S1, -C1);
    const float2 W4 = make_float2(0.f, -1.f);
    const float2 W6 = make_float2(-R2, -R2);
    const float2 W9 = make_float2(-C1, S1);
    float2 t[16];
#pragma unroll
    for (int m1 = 0; m1 < 4; ++m1)
        bfly4nt<SGN>(v[m1], v[m1 + 4], v[m1 + 8], v[m1 + 12],
                     t[4 * m1 + 0], t[4 * m1 + 1], t[4 * m1 + 2], t[4 * m1 + 3]);
    t[5]  = cmulsg<SGN>(W1, t[5]);
    t[6]  = cmulsg<SGN>(W2, t[6]);
    t[7]  = cmulsg<SGN>(W3, t[7]);
    t[9]  = cmulsg<SGN>(W2, t[9]);
    t[10] = cmulsg<SGN>(W4, t[10]);
    t[11] = cmulsg<SGN>(W6, t[11]);
    t[13] = cmulsg<SGN>(W3, t[13]);
    t[14] = cmulsg<SGN>(W6, t[14]);
    t[15] = cmulsg<SGN>(W9, t[15]);
#pragma unroll
    for (int j1 = 0; j1 < 4; ++j1)
        bfly4nt<SGN>(t[j1], t[4 + j1], t[8 + j1], t[12 + j1],
                     v[j1], v[j1 + 4], v[j1 + 8], v[j1 + 12]);
}

__device__ __forceinline__ float ftanh(float x) {
    float e = __expf(2.0f * x);
    return 1.0f - 2.0f * __builtin_amdgcn_rcpf(e + 1.0f);
}
// hann(n)/512 for the 512-window
__device__ __forceinline__ float hwin(int n) {
    return (0.5f - 0.5f * __cosf((float)n * 0.01227184630308513f)) * 0.001953125f;
}

// ---------------- kernel 1: channel mix + zero pad (unchanged, HBM-roof) ----
#define T_PAD  65792
__global__ __launch_bounds__(512, 1) void mix_kernel(const float* __restrict__ x,
                                                     const float* __restrict__ mixer,
                                                     float* __restrict__ mixed) {
    __shared__ __align__(16) float xt[64][128];
    __shared__ __align__(16) float mx[64][64];
    int tid = threadIdx.x;
    int b   = blockIdx.y;
    int t0  = blockIdx.x * 128;

    if (t0 >= T_LEN) {
        for (int f = tid; f < 8192; f += 512) {
            int d = f >> 7, tt = f & 127;
            mixed[((size_t)(b * C_CH + d)) * T_PAD + t0 + tt] = 0.0f;
        }
        return;
    }
    for (int f = tid; f < 4096; f += 512) reinterpret_cast<float*>(mx)[f] = mixer[f];
    for (int f4 = tid; f4 < 2048; f4 += 512) {
        int cc = f4 >> 5, tt4 = f4 & 31;
        *reinterpret_cast<float4*>(&xt[cc][tt4 * 4]) =
            *reinterpret_cast<const float4*>(&x[((size_t)(b * C_CH + cc)) * T_LEN + t0 + tt4 * 4]);
    }
    __syncthreads();

    int tp = tid & 63, grp = tid >> 6;
    int dbase = grp * 8;
    float2 acc[8];
#pragma unroll
    for (int i = 0; i < 8; ++i) acc[i] = make_float2(0.0f, 0.0f);
    for (int cc = 0; cc < 64; ++cc) {
        float2 xv = *reinterpret_cast<const float2*>(&xt[cc][2 * tp]);
        float4 m0 = *reinterpret_cast<const float4*>(&mx[cc][dbase + 0]);
        float4 m1 = *reinterpret_cast<const float4*>(&mx[cc][dbase + 4]);
        acc[0].x = fmaf(xv.x, m0.x, acc[0].x); acc[0].y = fmaf(xv.y, m0.x, acc[0].y);
        acc[1].x = fmaf(xv.x, m0.y, acc[1].x); acc[1].y = fmaf(xv.y, m0.y, acc[1].y);
        acc[2].x = fmaf(xv.x, m0.z, acc[2].x); acc[2].y = fmaf(xv.y, m0.z, acc[2].y);
        acc[3].x = fmaf(xv.x, m0.w, acc[3].x); acc[3].y = fmaf(xv.y, m0.w, acc[3].y);
        acc[4].x = fmaf(xv.x, m1.x, acc[4].x); acc[4].y = fmaf(xv.y, m1.x, acc[4].y);
        acc[5].x = fmaf(xv.x, m1.y, acc[5].x); acc[5].y = fmaf(xv.y, m1.y, acc[5].y);
        acc[6].x = fmaf(xv.x, m1.z, acc[6].x); acc[6].y = fmaf(xv.y, m1.z, acc[6].y);
        acc[7].x = fmaf(xv.x, m1.w, acc[7].x); acc[7].y = fmaf(xv.y, m1.w, acc[7].y);
    }
#pragma unroll
    for (int i = 0; i < 8; ++i)
        *reinterpret_cast<float2*>(&mixed[((size_t)(b * C_CH + dbase + i)) * T_PAD + t0 + 2 * tp]) = acc[i];
}

// -------- kernel 2: 16x16 four-step FFT, 16 lanes/frame, 32 frames/iter ----
__global__ __launch_bounds__(512, 2) void stft_kernel(const float* __restrict__ mixed,
                                                      const float* __restrict__ transfer,
                                                      const float* __restrict__ gainp,
                                                      float* __restrict__ out) {
    __shared__ __align__(16) float2 T[FPI * TPITCH];       // 70.7 KB, group-private rows
    __shared__ __align__(16) float2 spec[K_ * SPITCH];     // 67.8 KB, bin-major
    __shared__ __align__(16) float2 tails[2][132];

    const int tid  = threadIdx.x;
    const int bc   = blockIdx.x;
    const int b    = bc >> 6, c = bc & 63;
    const int gid  = tid >> 4;        // group (frame slot) 0..31
    const int l    = tid & 15;        // lane within group
    const int g    = tid >> 6;        // wave 0..7
    const int lane = tid & 63;

    const float2* src2 = reinterpret_cast<const float2*>(mixed + ((size_t)(b * C_CH + c)) * T_PAD);
    float2*       dst2 = reinterpret_cast<float2*>(out + ((size_t)(b * C_CH + c)) * T_LEN);

    // ---- per-lane constants
    const float TWO_PI = 6.2831853071795864f;
    float sn, cn;
    sincosf(TWO_PI * (float)l / 256.0f, &sn, &cn);
    const float2 w = make_float2(cn, -sn);          // e^{-2pi i l/256}
    float2 tw4[4], tw16[4];
    tw4[0] = make_float2(1.f, 0.f); tw4[1] = w;
    tw4[2] = cmul(w, w);            tw4[3] = cmul(tw4[2], w);
    float2 w4p = cmul(tw4[2], tw4[2]);              // w^4
    tw16[0] = make_float2(1.f, 0.f); tw16[1] = w4p;
    tw16[2] = cmul(w4p, w4p);        tw16[3] = cmul(tw16[2], w4p);
    sincosf(3.14159265358979f * (float)l / 256.0f, &sn, &cn);
    const float2 whl = make_float2(cn, -sn);        // e^{-i pi l/256}
    const float2 WHSTEP = make_float2(0.9807852804032304f, -0.1950903220161283f); // e^{-i pi/16}

    // ---- addresses
    const int tb  = gid * TPITCH;
    const int sl  = l & 12;
    const int l17 = l * 17;
    const int sb  = l * SPITCH + gid;               // spec bin (l+16k2): sb + 16*SPITCH*k2
    const int mbs = (256 - l) * SPITCH + gid;       // spec mirror: mbs - 16*SPITCH*k2
    const int mr  = (16 - l) & 15;
    const int mrb = tb + mr * 17;
    const int msw = mr & 12;

    // ---- scan: waves 0-3 (k = g*64+lane), wave 4 lane 0 -> k=256
    int sk = -1;
    if (g < 4) sk = g * 64 + lane;
    else if (g == 4 && lane == 0) sk = 256;
    float tk = 0.0f;
    float2 yc = make_float2(0.f, 0.f);
    if (sk >= 0) tk = transfer[c * K_ + sk];

    if (tid < 128) tails[1][tid] = make_float2(0.f, 0.f);
    const float gv = gainp[0];

    // ---- initial frame load (frame = gid), z[m] = float2 at f*128 + m, m = l+16*n2
    float2 v[16];
    {
        const float2* fp = src2 + (size_t)gid * 128;
#pragma unroll
        for (int n2 = 0; n2 < 16; ++n2) v[n2] = fp[l + 16 * n2];
    }
    BAR();

    for (int it = 0; it < NIT; ++it) {
        const int f = it * FPI + gid;
        // ================= P1: forward FFT =================
        dft16<1>(v);                                  // inner DFT over n2 -> index k1
#pragma unroll
        for (int k1 = 1; k1 < 16; ++k1) {             // twiddle W256^{l*k1}
            float2 z = v[k1];
            if (k1 & 3)  z = cmul(z, tw4[k1 & 3]);
            if (k1 >> 2) z = cmul(z, tw16[k1 >> 2]);
            v[k1] = z;
        }
#pragma unroll
        for (int a = 0; a < 8; ++a) {                 // matrix row l write (pairs)
            int p = tb + l17 + ((2 * a) ^ sl);
            *reinterpret_cast<float4*>(&T[p]) = make_float4(v[2*a].x, v[2*a].y, v[2*a+1].x, v[2*a+1].y);
        }
        CFENCE();
        // prefetch next iteration's frame (v is free)
        if (it + 1 < NIT) {
            const float2* fp = src2 + (size_t)(f + FPI) * 128;
#pragma unroll
            for (int n2 = 0; n2 < 16; ++n2) v[n2] = fp[l + 16 * n2];
        }
        // column read + outer DFT -> X[l + 16 k2]
        float2 cx[16];
#pragma unroll
        for (int n1 = 0; n1 < 16; ++n1) cx[n1] = T[tb + n1 * 17 + (l ^ (n1 & 12))];
        dft16<1>(cx);
        // X rows back into T (for mirror access)
#pragma unroll
        for (int a = 0; a < 8; ++a) {
            int p = tb + l17 + ((2 * a) ^ sl);
            *reinterpret_cast<float4*>(&T[p]) = make_float4(cx[2*a].x, cx[2*a].y, cx[2*a+1].x, cx[2*a+1].y);
        }
        CFENCE();
        // Hermitian split -> spec F[0..256]
        {
            float2 wh = whl;
#pragma unroll
            for (int k2 = 0; k2 < 16; ++k2) {
                int m2 = (l > 0) ? (15 - k2) : ((16 - k2) & 15);
                float2 xm = T[mrb + (m2 ^ msw)];
                float2 u  = cx[k2];
                float2 E = make_float2(0.5f * (u.x + xm.x),  0.5f * (u.y - xm.y));
                float2 O = make_float2(0.5f * (u.y + xm.y), -0.5f * (u.x - xm.x));
                spec[sb + 16 * SPITCH * k2] = cadd(E, cmulsg<1>(wh, O));
                wh = cmul(wh, WHSTEP);
            }
            if (l == 0) spec[256 * SPITCH + gid] = make_float2(cx[0].x - cx[0].y, 0.0f);
        }
        BAR();   // spec complete
        // ================= P2: scan =================
        if (sk >= 0) {
            float2* s0 = &spec[sk * SPITCH];
            float2 y = yc;
#pragma unroll
            for (int r = 0; r < 4; ++r) {
                float2 vv[8];
#pragma unroll
                for (int j = 0; j < 8; ++j) vv[j] = s0[r * 8 + j];
#pragma unroll
                for (int j = 0; j < 8; ++j) {
                    y.x = (vv[j].x + y.x) * tk; y.y = (vv[j].y + y.y) * tk;
                    s0[r * 8 + j] = y;
                }
            }
            yc = y;
        }
        BAR();   // scanned spec visible
        // ================= P3: inverse FFT =================
        float2 e[16];
        {
            float2 Gv[16];
            float2 wh = whl;
#pragma unroll
            for (int k2 = 0; k2 < 16; ++k2) {
                float2 u  = spec[sb + 16 * SPITCH * k2];
                float2 s2 = spec[mbs - 16 * SPITCH * k2];
                float2 A  = make_float2(u.x + s2.x, u.y - s2.y);
                float2 D  = make_float2(u.x - s2.x, u.y + s2.y);
                float2 Bv = cmulsg<-1>(wh, D);
                Gv[k2] = make_float2(A.x - Bv.y, A.y + Bv.x);
                wh = cmul(wh, WHSTEP);
            }
            dft16<-1>(Gv);                            // inner inverse over k2 -> n1
#pragma unroll
            for (int n1 = 1; n1 < 16; ++n1) {         // twiddle conj(w)^{n1}
                float2 z = Gv[n1];
                if (n1 & 3)  z = cmulsg<-1>(tw4[n1 & 3], z);
                if (n1 >> 2) z = cmulsg<-1>(tw16[n1 >> 2], z);
                Gv[n1] = z;
            }
#pragma unroll
            for (int a = 0; a < 8; ++a) {
                int p = tb + l17 + ((2 * a) ^ sl);
                *reinterpret_cast<float4*>(&T[p]) = make_float4(Gv[2*a].x, Gv[2*a].y, Gv[2*a+1].x, Gv[2*a+1].y);
            }
            CFENCE();
#pragma unroll
            for (int k1 = 0; k1 < 16; ++k1) e[k1] = T[tb + k1 * 17 + (l ^ (k1 & 12))];
            dft16<-1>(e);                             // -> x[l + 16 n2]
        }
        // publish windowed second half (n2 >= 8) for neighbor / tails
#pragma unroll
        for (int n2 = 8; n2 < 16; ++n2) {
            int m = l + 16 * n2;
            float2 sh = make_float2(e[n2].x * hwin(2 * m), e[n2].y * hwin(2 * m + 1));
            if (gid == FPI - 1) tails[it & 1][l + 16 * (n2 - 8)] = sh;
            else                T[tb + l + 16 * (n2 - 8)] = sh;
        }
        BAR();   // publishes visible
        // ================= P4: OLA + tanh + store (first half) =================
        {
            const float2* prow = (gid == 0) ? &tails[(it + 1) & 1][0] : &T[tb - TPITCH];
            float2* dp = dst2 + (size_t)f * 128;
#pragma unroll
            for (int n2 = 0; n2 < 8; ++n2) {
                int m = l + 16 * n2;
                float2 prev = prow[l + 16 * n2];
                float2 r;
                r.x = ftanh((e[n2].x * hwin(2 * m)     + prev.x) * gv);
                r.y = ftanh((e[n2].y * hwin(2 * m + 1) + prev.y) * gv);
                dp[m] = r;
            }
        }
        BAR();   // T rows free for next iteration
    }
}

extern "C" void kernel_launch(void* const* d_in, const int* in_sizes, int n_in,
                              void* d_out, int out_size, void* d_ws, size_t ws_size,
                              hipStream_t stream) {
    (void)in_sizes; (void)n_in; (void)out_size; (void)ws_size;
    const float* x        = (const float*)d_in[0];
    const float* mixer    = (const float*)d_in[1];
    const float* transfer = (const float*)d_in[2];
    const float* gain     = (const float*)d_in[3];
    float* out   = (float*)d_out;
    float* mixed = (float*)d_ws;   // (B, C, T_PAD) f32 = 67.4 MB

    dim3 gmix(T_PAD / 128, 4);
    mix_kernel<<<gmix, 512, 0, stream>>>(x, mixer, mixed);
    stft_kernel<<<256, 512, 0, stream>>>(mixed, transfer, gain, out);
}